// Round 11
// baseline (66.676 us; speedup 1.0000x reference)
//
#include <hip/hip_runtime.h>
#include <hip/hip_bf16.h>

#define WB 8192
#define WD 128
#define WC 100
#define NSPLIT 32
#define JSPL (WB/NSPLIT)   // 256 j per split
#define NTT (JSPL/16)      // 16 j-steps of 16 rows

typedef __attribute__((ext_vector_type(8))) short short8v;
typedef __attribute__((ext_vector_type(4))) float float4v;

#define SQS 3.798282f                 // sqrt((1/TAU)/ln2): fold scale into bf16 z
#define LN2F 0.69314718055994531f

#define EXP2(x) __builtin_amdgcn_exp2f(x)
#define LOG2(x) __builtin_amdgcn_logf(x)

// ---- workspace layout (bytes) ----
#define WS_ZBF   0u          // bf16 z (pre-scaled): 2097152
#define WS_CNT   2097152u    // cnt[128] int = 512          (memset: CNT..ACC+16)
#define WS_ACC   2097664u    // accf, accn, ticket, pad = 16
#define WS_LAB   2097680u    // labu8[8192] = 8192
#define WS_PM    2105872u    // partM[32][8192] f32 = 1048576
#define WS_PL    3154448u    // partL[32][8192] f32 = 1048576
#define WS_PP    4203024u    // partPS[32][8192] f32 = 1048576 (end 5251600)

__device__ __forceinline__ unsigned short f2bf(float x){
  unsigned u = __float_as_uint(x);
  u += 0x7fffu + ((u>>16)&1u);      // RNE
  return (unsigned short)(u>>16);
}

// blocks 0..511: convert+prescale z->bf16; 512..519: labels->u8 + histogram
__global__ __launch_bounds__(256) void k_prep(const float* __restrict__ z,
                                              const int* __restrict__ labels,
                                              unsigned short* __restrict__ zbf,
                                              unsigned* __restrict__ labu8,
                                              int* __restrict__ cnt){
  const int bid = blockIdx.x, t = threadIdx.x;
  if (bid < 512){
    int idx = bid*256 + t;
    const float4* zi = (const float4*)z;
    float4 a = zi[idx*2], b = zi[idx*2+1];
    uint4 o;
    o.x = (unsigned)f2bf(a.x*SQS) | ((unsigned)f2bf(a.y*SQS)<<16);
    o.y = (unsigned)f2bf(a.z*SQS) | ((unsigned)f2bf(a.w*SQS)<<16);
    o.z = (unsigned)f2bf(b.x*SQS) | ((unsigned)f2bf(b.y*SQS)<<16);
    o.w = (unsigned)f2bf(b.z*SQS) | ((unsigned)f2bf(b.w*SQS)<<16);
    ((uint4*)zbf)[idx] = o;
    return;
  }
  __shared__ int hist[128];
  const int cb = bid - 512;              // 8 blocks x 1024 labels
  if (t < 128) hist[t] = 0;
  __syncthreads();
  {  // pack 4 labels -> u32, and histogram
    int i = cb*1024 + t*4;
    int4 l4 = *(const int4*)(labels + i);
    labu8[cb*256 + t] = (unsigned)l4.x | ((unsigned)l4.y<<8)
                      | ((unsigned)l4.z<<16) | ((unsigned)l4.w<<24);
    atomicAdd(&hist[l4.x], 1); atomicAdd(&hist[l4.y], 1);
    atomicAdd(&hist[l4.z], 1); atomicAdd(&hist[l4.w], 1);
  }
  __syncthreads();
  if (t < 128 && hist[t] > 0) atomicAdd(&cnt[t], hist[t]);
}

template<bool DIAG>
__device__ __forceinline__ void lse_wave(const unsigned short* __restrict__ zbf,
                                         const unsigned* __restrict__ ldslab,
                                         const int* __restrict__ labels,
                                         int awave, int split, int lane,
                                         float* __restrict__ partM,
                                         float* __restrict__ partL,
                                         float* __restrict__ partPS){
  const int j0 = split*JSPL;
  const int lg = lane>>4, ln = lane&15;

  // anchor B-fragments: B[k][n]; lane: n=ln, k=kk*32+lg*8+e
  short8v bf[4][4];
  int labA[4];
  #pragma unroll
  for (int ss = 0; ss < 4; ss++){
    const unsigned short* zr = zbf + (size_t)(awave + ss*16 + ln)*WD;
    #pragma unroll
    for (int kk = 0; kk < 4; kk++)
      bf[ss][kk] = *(const short8v*)(zr + kk*32 + lg*8);
    labA[ss] = labels[awave + ss*16 + ln];
  }

  float m[4], l[4], ps[4];
  #pragma unroll
  for (int ss = 0; ss < 4; ss++){ m[ss] = -INFINITY; l[ss] = 0.f; ps[ss] = 0.f; }

  const unsigned short* ap = zbf + (size_t)(j0+ln)*WD + lg*8;
  short8v afA[4], afB[4];
#define LOADA(dst, tt) { const unsigned short* p_ = ap + (size_t)(tt)*16*WD; \
    dst[0] = *(const short8v*)(p_);      dst[1] = *(const short8v*)(p_+32);  \
    dst[2] = *(const short8v*)(p_+64);   dst[3] = *(const short8v*)(p_+96); }

#define COMPUTE(af, tt, lw) { \
    const int jb = j0 + (tt)*16; \
    const int b0 = (int)((lw)&255u),       b1 = (int)(((lw)>>8)&255u); \
    const int b2 = (int)(((lw)>>16)&255u), b3 = (int)((lw)>>24); \
    _Pragma("unroll") \
    for (int ss = 0; ss < 4; ss++){ \
      float4v acc = {0.f,0.f,0.f,0.f}; \
      _Pragma("unroll") \
      for (int kk = 0; kk < 4; kk++) \
        acc = __builtin_amdgcn_mfma_f32_16x16x32_bf16(af[kk], bf[ss][kk], acc, 0,0,0); \
      float v0 = acc[0], v1 = acc[1], v2 = acc[2], v3 = acc[3]; \
      if (DIAG){ \
        const bool dq = (jb == awave + ss*16); \
        const int r0 = lg*4; \
        ps[ss] += (((b0==labA[ss]) && !(dq&&(r0+0==ln))) ? v0 : 0.f) \
                + (((b1==labA[ss]) && !(dq&&(r0+1==ln))) ? v1 : 0.f) \
                + (((b2==labA[ss]) && !(dq&&(r0+2==ln))) ? v2 : 0.f) \
                + (((b3==labA[ss]) && !(dq&&(r0+3==ln))) ? v3 : 0.f); \
        if (dq){ \
          if (r0+0 == ln) v0 = -INFINITY; \
          if (r0+1 == ln) v1 = -INFINITY; \
          if (r0+2 == ln) v2 = -INFINITY; \
          if (r0+3 == ln) v3 = -INFINITY; \
        } \
      } else { \
        ps[ss] += ((b0==labA[ss]) ? v0 : 0.f) + ((b1==labA[ss]) ? v1 : 0.f) \
                + ((b2==labA[ss]) ? v2 : 0.f) + ((b3==labA[ss]) ? v3 : 0.f); \
      } \
      float tmax = fmaxf(fmaxf(v0,v1), fmaxf(v2,v3)); \
      float mn = fmaxf(m[ss], tmax); \
      l[ss] = l[ss]*EXP2(m[ss]-mn) \
            + ((EXP2(v0-mn) + EXP2(v1-mn)) + (EXP2(v2-mn) + EXP2(v3-mn))); \
      m[ss] = mn; \
    } }

  unsigned lwA = ldslab[lg];
  unsigned lwB = ldslab[4 + lg];
  LOADA(afA, 0); LOADA(afB, 1);
  for (int tt = 0; tt < NTT; tt += 2){
    COMPUTE(afA, tt, lwA);
    if (tt+2 < NTT){ LOADA(afA, tt+2); lwA = ldslab[(tt+2)*4 + lg]; }
    COMPUTE(afB, tt+1, lwB);
    if (tt+3 < NTT){ LOADA(afB, tt+3); lwB = ldslab[(tt+3)*4 + lg]; }
  }
#undef LOADA
#undef COMPUTE

  // combine lanes {x^16, x^32} (same anchor, different j-row groups)
  #pragma unroll
  for (int ss = 0; ss < 4; ss++){
    float mm = m[ss], ll = l[ss], pp = ps[ss];
    #pragma unroll
    for (int off = 16; off < 64; off <<= 1){
      float mo = __shfl_xor(mm, off);
      float lo = __shfl_xor(ll, off);
      float M = fmaxf(mm, mo);
      ll = ll*EXP2(mm-M) + lo*EXP2(mo-M);
      mm = M;
      pp += __shfl_xor(pp, off);
    }
    if (lane < 16){
      size_t o = (size_t)split*WB + awave + ss*16 + lane;
      partM[o] = mm; partL[o] = ll; partPS[o] = pp;
    }
  }
}

// 1024 blocks x 256 (4 waves). All 4 waves share one split; each wave owns 64 anchors.
// XCD owns 4 splits: j-window 4*256 rows (256 KB) + anchors (2 MB) < 4 MB L2.
__global__ __launch_bounds__(256) void k_lse(const unsigned short* __restrict__ zbf,
                                             const int* __restrict__ labels,
                                             const unsigned* __restrict__ labu8,
                                             float* __restrict__ partM,
                                             float* __restrict__ partL,
                                             float* __restrict__ partPS){
  __shared__ unsigned ldslab[JSPL/4];      // 64 words = this split's 256 labels
  const int t = threadIdx.x, wv = t>>6, lane = t&63;
  const int bid = blockIdx.x;
  const int xcd = bid & 7, chunk = bid >> 3;         // chunk 0..127
  const int split = (xcd<<2) | (chunk & 3);          // 0..31
  const int ablk  = ((chunk>>2)<<2) | wv;            // 0..127
  const int awave = ablk*64;
  const int j0 = split*JSPL;

  if (t < JSPL/4) ldslab[t] = labu8[(j0>>2) + t];
  __syncthreads();

  if ((awave >> 8) == split)
    lse_wave<true >(zbf, ldslab, labels, awave, split, lane, partM, partL, partPS);
  else
    lse_wave<false>(zbf, ldslab, labels, awave, split, lane, partM, partL, partPS);
}

// 32 blocks x 256 threads: one anchor per thread.
__global__ __launch_bounds__(256) void k_final(const int* __restrict__ labels,
                                               const int* __restrict__ cnt,
                                               const float* __restrict__ partM,
                                               const float* __restrict__ partL,
                                               const float* __restrict__ partPS,
                                               float* accf, int* accn, int* ticket,
                                               float* __restrict__ out){
  const int t = threadIdx.x;
  const int a = blockIdx.x*256 + t;
  float mm = -INFINITY;
  #pragma unroll 8
  for (int sp = 0; sp < NSPLIT; sp++)
    mm = fmaxf(mm, partM[(size_t)sp*WB + a]);
  float ll = 0.f, pp = 0.f;
  #pragma unroll 8
  for (int sp = 0; sp < NSPLIT; sp++){
    ll = fmaf(partL[(size_t)sp*WB + a], EXP2(partM[(size_t)sp*WB + a] - mm), ll);
    pp += partPS[(size_t)sp*WB + a];
  }
  float lse2 = mm + LOG2(ll);             // log2 units
  int lab = labels[a];
  int np = cnt[lab] - 1;
  float loss = 0.f, val = 0.f;
  if (np > 0){ loss = LN2F*(lse2 - pp/(float)np); val = 1.f; }
  #pragma unroll
  for (int off = 32; off > 0; off >>= 1){
    loss += __shfl_down(loss, off);
    val  += __shfl_down(val,  off);
  }
  __shared__ float sl[4], sv[4];
  int wv = t>>6, lane = t&63;
  if (lane == 0){ sl[wv] = loss; sv[wv] = val; }
  __syncthreads();
  if (t == 0){
    atomicAdd(accf, sl[0]+sl[1]+sl[2]+sl[3]);
    atomicAdd(accn, (int)(sv[0]+sv[1]+sv[2]+sv[3] + 0.5f));
    __threadfence();
    int tk = atomicAdd(ticket, 1);
    if (tk == 31){                         // last block finalizes
      float f = atomicAdd(accf, 0.f);
      int   n = atomicAdd(accn, 0);
      out[0] = f / (float)max(n, 1);
    }
  }
}

extern "C" void kernel_launch(void* const* d_in, const int* in_sizes, int n_in,
                              void* d_out, int out_size, void* d_ws, size_t ws_size,
                              hipStream_t stream){
  const float* z = (const float*)d_in[0];
  const int* labels = (const int*)d_in[1];
  char* ws = (char*)d_ws;
  unsigned short* zbf = (unsigned short*)(ws + WS_ZBF);
  int*      cnt    = (int*)(ws + WS_CNT);
  float*    accf   = (float*)(ws + WS_ACC);
  int*      accn   = (int*)(ws + WS_ACC + 4);
  int*      ticket = (int*)(ws + WS_ACC + 8);
  unsigned* labu8  = (unsigned*)(ws + WS_LAB);
  float*    partM  = (float*)(ws + WS_PM);
  float*    partL  = (float*)(ws + WS_PL);
  float*    partPS = (float*)(ws + WS_PP);
  float* out = (float*)d_out;

  hipMemsetAsync(ws + WS_CNT, 0, 512 + 16, stream);   // cnt + acc/ticket
  hipLaunchKernelGGL(k_prep,  dim3(520),  dim3(256), 0, stream,
                     z, labels, zbf, labu8, cnt);
  hipLaunchKernelGGL(k_lse,   dim3(1024), dim3(256), 0, stream,
                     zbf, labels, labu8, partM, partL, partPS);
  hipLaunchKernelGGL(k_final, dim3(32),   dim3(256), 0, stream,
                     labels, cnt, partM, partL, partPS, accf, accn, ticket, out);
}

// Round 12
// 64.884 us; speedup vs baseline: 1.0276x; 1.0276x over previous
//
#include <hip/hip_runtime.h>
#include <hip/hip_bf16.h>

#define WB 8192
#define WD 128
#define WC 100
#define NSPLIT 32
#define JSPL (WB/NSPLIT)   // 256 j per split
#define NTT (JSPL/16)      // 16 j-steps of 16 rows

typedef __attribute__((ext_vector_type(8))) short short8v;
typedef __attribute__((ext_vector_type(4))) float float4v;

#define SQS 3.798282f                 // sqrt((1/TAU)/ln2): fold scale into bf16 z
#define LN2F 0.69314718055994531f

#define EXP2(x) __builtin_amdgcn_exp2f(x)
#define LOG2(x) __builtin_amdgcn_logf(x)

// ---- workspace layout (bytes) ----
#define WS_ZBF   0u          // bf16 z (pre-scaled): 2097152
#define WS_CNT   2097152u    // cnt[128] int = 512          (memset: CNT..ACC+16)
#define WS_ACC   2097664u    // accf, accn, ticket, pad = 16
#define WS_LAB   2097680u    // labu8[8192] = 8192
#define WS_PM    2105872u    // partM[32][8192] f32 = 1048576
#define WS_PL    3154448u    // partL[32][8192] f32 = 1048576
#define WS_PP    4203024u    // partPS[32][8192] f32 = 1048576 (end 5251600)

__device__ __forceinline__ unsigned short f2bf(float x){
  unsigned u = __float_as_uint(x);
  u += 0x7fffu + ((u>>16)&1u);      // RNE
  return (unsigned short)(u>>16);
}

// blocks 0..511: convert+prescale z->bf16; 512..519: labels->u8 + histogram
__global__ __launch_bounds__(256) void k_prep(const float* __restrict__ z,
                                              const int* __restrict__ labels,
                                              unsigned short* __restrict__ zbf,
                                              unsigned* __restrict__ labu8,
                                              int* __restrict__ cnt){
  const int bid = blockIdx.x, t = threadIdx.x;
  if (bid < 512){
    int idx = bid*256 + t;
    const float4* zi = (const float4*)z;
    float4 a = zi[idx*2], b = zi[idx*2+1];
    uint4 o;
    o.x = (unsigned)f2bf(a.x*SQS) | ((unsigned)f2bf(a.y*SQS)<<16);
    o.y = (unsigned)f2bf(a.z*SQS) | ((unsigned)f2bf(a.w*SQS)<<16);
    o.z = (unsigned)f2bf(b.x*SQS) | ((unsigned)f2bf(b.y*SQS)<<16);
    o.w = (unsigned)f2bf(b.z*SQS) | ((unsigned)f2bf(b.w*SQS)<<16);
    ((uint4*)zbf)[idx] = o;
    return;
  }
  __shared__ int hist[128];
  const int cb = bid - 512;              // 8 blocks x 1024 labels
  if (t < 128) hist[t] = 0;
  __syncthreads();
  {  // pack 4 labels -> u32, and histogram
    int i = cb*1024 + t*4;
    int4 l4 = *(const int4*)(labels + i);
    labu8[cb*256 + t] = (unsigned)l4.x | ((unsigned)l4.y<<8)
                      | ((unsigned)l4.z<<16) | ((unsigned)l4.w<<24);
    atomicAdd(&hist[l4.x], 1); atomicAdd(&hist[l4.y], 1);
    atomicAdd(&hist[l4.z], 1); atomicAdd(&hist[l4.w], 1);
  }
  __syncthreads();
  if (t < 128 && hist[t] > 0) atomicAdd(&cnt[t], hist[t]);
}

// 1024 blocks x 256 (4 waves). All 4 waves share one split; A-tile staged in LDS
// once per block (4x traffic cut), double-buffered, XOR-swizzled.
__global__ __launch_bounds__(256) void k_lse(const unsigned short* __restrict__ zbf,
                                             const int* __restrict__ labels,
                                             const unsigned* __restrict__ labu8,
                                             float* __restrict__ partM,
                                             float* __restrict__ partL,
                                             float* __restrict__ partPS){
  __shared__ __align__(16) unsigned char atile[2][16*256];  // 2 x 4 KB
  __shared__ unsigned ldslab[JSPL/4];      // 64 words = this split's 256 labels
  const int t = threadIdx.x, wv = t>>6, lane = t&63;
  const int bid = blockIdx.x;
  const int xcd = bid & 7, chunk = bid >> 3;         // chunk 0..127
  const int split = (xcd<<2) | (chunk & 3);          // 0..31
  const int ablk  = ((chunk>>2)<<2) | wv;            // 0..127
  const int awave = ablk*64;
  const int j0 = split*JSPL;
  const int lg = lane>>4, ln = lane&15;
  const bool DIAG = ((awave >> 8) == split);

  // staging addresses for this thread
  const int srow = t>>4, sck = t&15;                 // row 0..15, 16B chunk 0..15
  const unsigned swoff = srow*256 + ((sck*16) ^ ((srow&7)<<4));
  const unsigned short* sbase = zbf + (size_t)(j0 + srow)*WD + sck*8;

  if (t < JSPL/4) ldslab[t] = labu8[(j0>>2) + t];

  // anchor B-fragments: B[k][n]; lane: n=ln, k=kk*32+lg*8+e
  short8v bf[4][4];
  int labA[4];
  #pragma unroll
  for (int ss = 0; ss < 4; ss++){
    const unsigned short* zr = zbf + (size_t)(awave + ss*16 + ln)*WD;
    #pragma unroll
    for (int kk = 0; kk < 4; kk++)
      bf[ss][kk] = *(const short8v*)(zr + kk*32 + lg*8);
    labA[ss] = labels[awave + ss*16 + ln];
  }

  float m[4], l[4], ps[4];
  #pragma unroll
  for (int ss = 0; ss < 4; ss++){ m[ss] = -INFINITY; l[ss] = 0.f; ps[ss] = 0.f; }

  // prologue: stage tile 0 into buf 0
  {
    uint4 v = *(const uint4*)sbase;
    *(uint4*)&atile[0][swoff] = v;
  }
  __syncthreads();

  // lds read offsets for the 4 A-fragments of this lane
  const unsigned roff0 = ln*256 + ((0*64 + lg*16) ^ ((ln&7)<<4));
  const unsigned roff1 = ln*256 + ((1*64 + lg*16) ^ ((ln&7)<<4));
  const unsigned roff2 = ln*256 + ((2*64 + lg*16) ^ ((ln&7)<<4));
  const unsigned roff3 = ln*256 + ((3*64 + lg*16) ^ ((ln&7)<<4));

  unsigned lw = ldslab[lg];
  int cur = 0;
  for (int tt = 0; tt < NTT; tt++){
    // issue next tile's global load early (T14 async split)
    uint4 nld;
    const bool have = (tt+1 < NTT);
    if (have) nld = *(const uint4*)(sbase + (size_t)(tt+1)*16*WD);
    unsigned lwN = (have) ? ldslab[(tt+1)*4 + lg] : 0u;

    // A-fragments from LDS (shared by all 4 ss)
    short8v af0 = *(const short8v*)&atile[cur][roff0];
    short8v af1 = *(const short8v*)&atile[cur][roff1];
    short8v af2 = *(const short8v*)&atile[cur][roff2];
    short8v af3 = *(const short8v*)&atile[cur][roff3];

    const int jb = j0 + tt*16;
    const int b0 = (int)(lw&255u),       b1 = (int)((lw>>8)&255u);
    const int b2 = (int)((lw>>16)&255u), b3 = (int)(lw>>24);
    #pragma unroll
    for (int ss = 0; ss < 4; ss++){
      float4v acc = {0.f,0.f,0.f,0.f};
      acc = __builtin_amdgcn_mfma_f32_16x16x32_bf16(af0, bf[ss][0], acc, 0,0,0);
      acc = __builtin_amdgcn_mfma_f32_16x16x32_bf16(af1, bf[ss][1], acc, 0,0,0);
      acc = __builtin_amdgcn_mfma_f32_16x16x32_bf16(af2, bf[ss][2], acc, 0,0,0);
      acc = __builtin_amdgcn_mfma_f32_16x16x32_bf16(af3, bf[ss][3], acc, 0,0,0);
      float v0 = acc[0], v1 = acc[1], v2 = acc[2], v3 = acc[3];
      if (DIAG){
        const bool dq = (jb == awave + ss*16);
        const int r0 = lg*4;
        ps[ss] += (((b0==labA[ss]) && !(dq&&(r0+0==ln))) ? v0 : 0.f)
                + (((b1==labA[ss]) && !(dq&&(r0+1==ln))) ? v1 : 0.f)
                + (((b2==labA[ss]) && !(dq&&(r0+2==ln))) ? v2 : 0.f)
                + (((b3==labA[ss]) && !(dq&&(r0+3==ln))) ? v3 : 0.f);
        if (dq){
          if (r0+0 == ln) v0 = -INFINITY;
          if (r0+1 == ln) v1 = -INFINITY;
          if (r0+2 == ln) v2 = -INFINITY;
          if (r0+3 == ln) v3 = -INFINITY;
        }
      } else {
        ps[ss] += ((b0==labA[ss]) ? v0 : 0.f) + ((b1==labA[ss]) ? v1 : 0.f)
                + ((b2==labA[ss]) ? v2 : 0.f) + ((b3==labA[ss]) ? v3 : 0.f);
      }
      // defer-max (T13): common path has NO exp2 in the carried chain
      float tmax = fmaxf(fmaxf(v0,v1), fmaxf(v2,v3));
      if (__any(tmax > m[ss] + 8.0f)){
        float mn = fmaxf(m[ss], tmax);
        l[ss] *= EXP2(m[ss]-mn);
        m[ss] = mn;
      }
      l[ss] += (EXP2(v0-m[ss]) + EXP2(v1-m[ss]))
             + (EXP2(v2-m[ss]) + EXP2(v3-m[ss]));
    }

    // write next tile into the other buffer, then one barrier
    if (have) *(uint4*)&atile[cur^1][swoff] = nld;
    __syncthreads();
    lw = lwN;
    cur ^= 1;
  }

  // combine lanes {x^16, x^32} (same anchor, different j-row groups)
  #pragma unroll
  for (int ss = 0; ss < 4; ss++){
    float mm = m[ss], ll = l[ss], pp = ps[ss];
    #pragma unroll
    for (int off = 16; off < 64; off <<= 1){
      float mo = __shfl_xor(mm, off);
      float lo = __shfl_xor(ll, off);
      float M = fmaxf(mm, mo);
      ll = ll*EXP2(mm-M) + lo*EXP2(mo-M);
      mm = M;
      pp += __shfl_xor(pp, off);
    }
    if (lane < 16){
      size_t o = (size_t)split*WB + awave + ss*16 + lane;
      partM[o] = mm; partL[o] = ll; partPS[o] = pp;
    }
  }
}

// 32 blocks x 256 threads: one anchor per thread.
__global__ __launch_bounds__(256) void k_final(const int* __restrict__ labels,
                                               const int* __restrict__ cnt,
                                               const float* __restrict__ partM,
                                               const float* __restrict__ partL,
                                               const float* __restrict__ partPS,
                                               float* accf, int* accn, int* ticket,
                                               float* __restrict__ out){
  const int t = threadIdx.x;
  const int a = blockIdx.x*256 + t;
  float mm = -INFINITY;
  #pragma unroll 8
  for (int sp = 0; sp < NSPLIT; sp++)
    mm = fmaxf(mm, partM[(size_t)sp*WB + a]);
  float ll = 0.f, pp = 0.f;
  #pragma unroll 8
  for (int sp = 0; sp < NSPLIT; sp++){
    ll = fmaf(partL[(size_t)sp*WB + a], EXP2(partM[(size_t)sp*WB + a] - mm), ll);
    pp += partPS[(size_t)sp*WB + a];
  }
  float lse2 = mm + LOG2(ll);             // log2 units
  int lab = labels[a];
  int np = cnt[lab] - 1;
  float loss = 0.f, val = 0.f;
  if (np > 0){ loss = LN2F*(lse2 - pp/(float)np); val = 1.f; }
  #pragma unroll
  for (int off = 32; off > 0; off >>= 1){
    loss += __shfl_down(loss, off);
    val  += __shfl_down(val,  off);
  }
  __shared__ float sl[4], sv[4];
  int wv = t>>6, lane = t&63;
  if (lane == 0){ sl[wv] = loss; sv[wv] = val; }
  __syncthreads();
  if (t == 0){
    atomicAdd(accf, sl[0]+sl[1]+sl[2]+sl[3]);
    atomicAdd(accn, (int)(sv[0]+sv[1]+sv[2]+sv[3] + 0.5f));
    __threadfence();
    int tk = atomicAdd(ticket, 1);
    if (tk == 31){                         // last block finalizes
      float f = atomicAdd(accf, 0.f);
      int   n = atomicAdd(accn, 0);
      out[0] = f / (float)max(n, 1);
    }
  }
}

extern "C" void kernel_launch(void* const* d_in, const int* in_sizes, int n_in,
                              void* d_out, int out_size, void* d_ws, size_t ws_size,
                              hipStream_t stream){
  const float* z = (const float*)d_in[0];
  const int* labels = (const int*)d_in[1];
  char* ws = (char*)d_ws;
  unsigned short* zbf = (unsigned short*)(ws + WS_ZBF);
  int*      cnt    = (int*)(ws + WS_CNT);
  float*    accf   = (float*)(ws + WS_ACC);
  int*      accn   = (int*)(ws + WS_ACC + 4);
  int*      ticket = (int*)(ws + WS_ACC + 8);
  unsigned* labu8  = (unsigned*)(ws + WS_LAB);
  float*    partM  = (float*)(ws + WS_PM);
  float*    partL  = (float*)(ws + WS_PL);
  float*    partPS = (float*)(ws + WS_PP);
  float* out = (float*)d_out;

  hipMemsetAsync(ws + WS_CNT, 0, 512 + 16, stream);   // cnt + acc/ticket
  hipLaunchKernelGGL(k_prep,  dim3(520),  dim3(256), 0, stream,
                     z, labels, zbf, labu8, cnt);
  hipLaunchKernelGGL(k_lse,   dim3(1024), dim3(256), 0, stream,
                     zbf, labels, labu8, partM, partL, partPS);
  hipLaunchKernelGGL(k_final, dim3(32),   dim3(256), 0, stream,
                     labels, cnt, partM, partL, partPS, accf, accn, ticket, out);
}